// Round 12
// baseline (249.508 us; speedup 1.0000x reference)
//
#include <hip/hip_runtime.h>
#include <cstdint>
#include <cstddef>

constexpr int Bsz   = 2;
constexpr int Nseq  = 4096;
constexpr int NH    = 8;
constexpr int HD    = 64;
constexpr int MODEL = NH * HD;   // 512
constexpr int BR    = 256;       // q-rows per block: 4 waves x 64 (2 subtiles of 32)
constexpr int BC    = 128;       // keys per tile (4 sub-tiles of 32)
constexpr int NT    = Nseq / BC; // 32 key tiles
constexpr int ROWS  = Bsz * Nseq;   // 8192

// 0.125 (1/sqrt(64)) * log2(e): exp(s) = exp2(s*log2e) with log2e folded into Q.
constexpr float QSCALE = 0.18033688011112042f;

typedef _Float16 f16;
typedef f16   f16x2 __attribute__((ext_vector_type(2)));
typedef f16   f16x8 __attribute__((ext_vector_type(8)));
typedef float f32x16 __attribute__((ext_vector_type(16)));

__device__ __forceinline__ unsigned pku(float a, float b) {
    auto r = __builtin_amdgcn_cvt_pkrtz(a, b);   // packed f32->f16 (RTZ), 1 instr
    return __builtin_bit_cast(unsigned, r);
}

__device__ __forceinline__ float fast_exp2(float x) {
#if __has_builtin(__builtin_amdgcn_exp2f)
    return __builtin_amdgcn_exp2f(x);
#else
    return exp2f(x);
#endif
}

__device__ __forceinline__ f32x16 z16() {
    f32x16 v;
#pragma unroll
    for (int i = 0; i < 16; ++i) v[i] = 0.f;
    return v;
}

__device__ __forceinline__ f32x16 mfma32(f16x8 a, f16x8 b, f32x16 c) {
    return __builtin_amdgcn_mfma_f32_32x32x16_f16(a, b, c, 0, 0, 0);
}

// Flash attention + fused per-head output projection.
// v12 = v11 (verified best: 64 q-rows/wave, NSPLIT=2, 2 waves/SIMD, work cuts)
// + SCHEDULE attack (v11 diagnostic: MFMA 27% + VALU 33%, ~40% dependency stalls;
// no pipe is the bottleneck — the emitted order alternates pipes instead of
// overlapping them):
//  * BC=128: 4 key-sub-tiles of 32 per LDS tile; barriers halved (16/block),
//    4x longer straight-line scheduling region. LDS 64 KB/block x 2 blocks.
//  * explicit 4-stage pipeline per kt: qk(i+1) || pv(i) || exp(i+1) — pv(i)'s
//    MFMAs (dep only on exp(i)) fill the matrix pipe while exp(i+1) runs on
//    VALU. Two alternating pb register sets, all statically indexed.
// Register budget: ~155 arch + 64 AGPR ~= 220 unified < 256 cap of
// __launch_bounds__(256,2) -> no spill possible (v8/v9 lesson).
// Math identical to v7..v11 (all passed, absmax 4.9e-4): no-max-shift softmax
// (log2e folded into QSCALE), S^T = mfma(A=K,B=Q), operand-swapped PV
// O^T = mfma(A=V^T,B=P^T) (P stays in-lane; V staged with key-bits 2<->3
// swapped so A-frags are contiguous b128 reads), l row-sum in VALU, fused
// split-f16 projection Y_s=(O_s/l_s)@W_h; combine sums Y_s*l_s/(sum l) + bias.
template<int NSPLIT>
__global__ __launch_bounds__(256, 2) void flash_attn_fused_kernel(
        const float* __restrict__ Q,
        const float* __restrict__ K,
        const float* __restrict__ V,
        const float* __restrict__ W,
        float* __restrict__ Ypart,
        float* __restrict__ lpart) {
    __shared__ __align__(16) f16 Ks[2][BC * 64];   // 2 x 16 KB  [key][d]
    __shared__ __align__(16) f16 Vt[2][HD * BC];   // 2 x 16 KB  [d][key]

    constexpr int NTL = NT / NSPLIT;   // key tiles per block

    const int wg = blockIdx.x;
    int qtile, bh, s;
    if constexpr (NSPLIT == 2) {
        // 512 blocks, 64 contiguous work-ids per XCD; both splits of one
        // (qtile,bh) on the same XCD -> K/V slices in its private L2 (v7: 25 MB).
        const int g = (wg & 7) * 64 + (wg >> 3);
        s = g & 1; qtile = (g >> 1) & 15; bh = g >> 5;
    } else {
        const int g = (wg & 7) * 32 + (wg >> 3);
        s = 0; qtile = g & 15; bh = g >> 4;
    }
    const int b   = bh >> 3;
    const int h   = bh & 7;
    const int kt0 = s * NTL;

    const int t    = threadIdx.x;
    const int lane = t & 63;
    const int wave = t >> 6;        // 0..3, 64 q-rows each
    const int l31  = lane & 31;
    const int H    = lane >> 5;     // half-wave

    // ---- Q fragments (B-operand: n=lane&31=q, chunk c: d = c*16 + H*8 + j); QSCALE folded ----
    f16x8 qf[2][4];
#pragma unroll
    for (int tile = 0; tile < 2; ++tile) {
        const int    qrow = qtile * BR + wave * 64 + tile * 32 + l31;
        const float* qp   = Q + ((size_t)(b * Nseq + qrow)) * MODEL + h * HD + H * 8;
#pragma unroll
        for (int c = 0; c < 4; ++c) {
            float4 a0 = *(const float4*)(qp + c * 16);
            float4 a1 = *(const float4*)(qp + c * 16 + 4);
            union { unsigned w[4]; f16x8 v; } u;
            u.w[0] = pku(a0.x * QSCALE, a0.y * QSCALE);
            u.w[1] = pku(a0.z * QSCALE, a0.w * QSCALE);
            u.w[2] = pku(a1.x * QSCALE, a1.y * QSCALE);
            u.w[3] = pku(a1.z * QSCALE, a1.w * QSCALE);
            qf[tile][c] = u.v;
        }
    }

    f32x16 oacc[2][2];   // [tile][D]: O^T[d = 32D + rho(H,r)][q = l31]
#pragma unroll
    for (int tile = 0; tile < 2; ++tile) {
        oacc[tile][0] = z16(); oacc[tile][1] = z16();
    }
    float lsum[2] = {0.f, 0.f};   // [tile]: partial denom over this lane's H-half keys

    // ---- staging assignments (256 threads, 128-key tile) ----
    const int ka  = t & 7;          // K: chunk 0..7 (8 f16)
    const int kr  = t >> 3;         // K: rows kr + 32*rr, rr=0..3
    const int vkp = t & 63;         // V: key pair (keys 2vkp, 2vkp+1), 0..63
    // pi swaps key bits 2,3 -> pair-index bits 1,2 (6-bit pair index)
    const int vps = (vkp & 0x39) | ((vkp & 2) << 1) | ((vkp & 4) >> 1);
    const int vd0 = (t >> 6) * 16;  // V: 16 d's

    // staging registers: f16-packed at load (u32 pairs)
    unsigned kpk[16];   // [4*rr+i]: row kr+32rr, d-pair (2i,2i+1) of this thread's chunk
    unsigned vpk[16];   // [i]: d = vd0+i, keys (2vkp, 2vkp+1)

    auto loadtile = [&](int kt_) {   // GLOBAL tile index; packs to f16 at load
#pragma unroll
        for (int rr = 0; rr < 4; ++rr) {
            const float* kp = K + ((size_t)(b * Nseq + kt_ * BC + kr + 32 * rr)) * MODEL + h * HD + ka * 8;
            float4 a = *(const float4*)kp;
            float4 c = *(const float4*)(kp + 4);
            kpk[4 * rr + 0] = pku(a.x, a.y);
            kpk[4 * rr + 1] = pku(a.z, a.w);
            kpk[4 * rr + 2] = pku(c.x, c.y);
            kpk[4 * rr + 3] = pku(c.z, c.w);
        }
        const float* vp = V + ((size_t)(b * Nseq + kt_ * BC + 2 * vkp)) * MODEL + h * HD + vd0;
#pragma unroll
        for (int j = 0; j < 4; ++j) {
            float4 v0 = *(const float4*)(vp + 4 * j);
            float4 v1 = *(const float4*)(vp + MODEL + 4 * j);
            vpk[4 * j + 0] = pku(v0.x, v1.x);
            vpk[4 * j + 1] = pku(v0.y, v1.y);
            vpk[4 * j + 2] = pku(v0.z, v1.z);
            vpk[4 * j + 3] = pku(v0.w, v1.w);
        }
    };

    auto stage = [&](int pb_) {
        // K: full 8-f16 chunk per (row,chunk), b128 writes, swizzle chunk ^ (row&7)
#pragma unroll
        for (int rr = 0; rr < 4; ++rr) {
            const int row = kr + 32 * rr;
            union { unsigned w[4]; f16x8 v; } u;
            u.w[0] = kpk[4 * rr + 0]; u.w[1] = kpk[4 * rr + 1];
            u.w[2] = kpk[4 * rr + 2]; u.w[3] = kpk[4 * rr + 3];
            *(f16x8*)&Ks[pb_][row * 64 + ((ka ^ (row & 7)) << 3)] = u.v;
        }
        // V: transposed, pi-permuted pair position vps, 16B-chunk swizzle ^ (d&15)
#pragma unroll
        for (int i = 0; i < 16; ++i) {
            const int d = vd0 + i;
            *(unsigned*)&Vt[pb_][d * BC + (((vps >> 2) ^ (d & 15)) << 3) + ((vps & 3) << 1)] = vpk[i];
        }
    };

    // ---- pipeline stage helpers (all statically indexed at call sites) ----
    auto qk_sub = [&](int sub, f32x16 &sA, f32x16 &sB, int pbuf) {
        const int krow = sub * 32 + l31;
        const int swz  = l31 & 7;
        __builtin_amdgcn_s_setprio(1);
#pragma unroll
        for (int c = 0; c < 4; ++c) {
            const f16x8 kf = *(const f16x8*)&Ks[pbuf][krow * 64 + (((2 * c + H) ^ swz) << 3)];
            sA = mfma32(kf, qf[0][c], sA);
            sB = mfma32(kf, qf[1][c], sB);
        }
        __builtin_amdgcn_s_setprio(0);
    };
    auto exp_sub = [&](const f32x16 &sA, const f32x16 &sB, f16x8 (&pbo)[2][2]) {
#pragma unroll
        for (int tile = 0; tile < 2; ++tile) {
            const f32x16 sv = tile ? sB : sA;
            union { unsigned w[4]; f16x8 v; } w0, w1;
            float a0 = 0.f, a1 = 0.f;
#pragma unroll
            for (int i = 0; i < 4; ++i) {
                float p0 = fast_exp2(sv[2 * i]);
                float p1 = fast_exp2(sv[2 * i + 1]);
                w0.w[i] = pku(p0, p1);
                a0 += p0 + p1;
            }
#pragma unroll
            for (int i = 0; i < 4; ++i) {
                float p0 = fast_exp2(sv[8 + 2 * i]);
                float p1 = fast_exp2(sv[8 + 2 * i + 1]);
                w1.w[i] = pku(p0, p1);
                a1 += p0 + p1;
            }
            lsum[tile] += a0 + a1;
            pbo[tile][0] = w0.v;
            pbo[tile][1] = w1.v;
        }
    };
    auto pv_sub = [&](int sub, const f16x8 (&pbi)[2][2], int pbuf) {
        __builtin_amdgcn_s_setprio(1);
#pragma unroll
        for (int g = 0; g < 2; ++g) {
#pragma unroll
            for (int D = 0; D < 2; ++D) {
                const int d = D * 32 + l31;
                const f16x8 vf = *(const f16x8*)&Vt[pbuf][d * BC + (((4 * sub + 2 * g + H) ^ (d & 15)) << 3)];
                oacc[0][D] = mfma32(vf, pbi[0][g], oacc[0][D]);
                oacc[1][D] = mfma32(vf, pbi[1][g], oacc[1][D]);
            }
        }
        __builtin_amdgcn_s_setprio(0);
    };

    // ---- prologue: buf0 <- tile kt0; regs <- tile kt0+1 ----
    loadtile(kt0);
    stage(0);
    loadtile(kt0 + 1);
    __syncthreads();

    int p = 0;
    for (int lt = 0; lt < NTL; ++lt) {
        f16x8 pbA[2][2], pbB[2][2];
        f32x16 sA, sB;
        // 4-stage pipeline: qk(i+1) || pv(i) || exp(i+1)
        sA = z16(); sB = z16(); qk_sub(0, sA, sB, p); exp_sub(sA, sB, pbA);
        sA = z16(); sB = z16(); qk_sub(1, sA, sB, p); pv_sub(0, pbA, p); exp_sub(sA, sB, pbB);
        sA = z16(); sB = z16(); qk_sub(2, sA, sB, p); pv_sub(1, pbB, p); exp_sub(sA, sB, pbA);
        if (lt + 1 < NTL) stage(p ^ 1);
        if (lt + 2 < NTL) loadtile(kt0 + lt + 2);
        sA = z16(); sB = z16(); qk_sub(3, sA, sB, p); pv_sub(2, pbA, p); exp_sub(sA, sB, pbB);
        pv_sub(3, pbB, p);
        __syncthreads();   // buf[p^1] staged & visible; all reads of buf[p] done
        p ^= 1;
    }

    // ---- fused epilogue (per subtile): complete l, normalize, split-f16, W_h ----
#pragma unroll
    for (int tile = 0; tile < 2; ++tile) {
        // this lane holds the H-half partial; the complement lives at lane^32
        const float l_all = lsum[tile] + __shfl_xor(lsum[tile], 32, 64);
        const float inv   = 1.0f / l_all;

        if constexpr (NSPLIT >= 2) {   // store partial denominator
            if (H == 0)
                lpart[(size_t)(s * NH + h) * ROWS + b * Nseq
                      + qtile * BR + wave * 64 + tile * 32 + l31] = l_all;
        }

        // O^T regs -> A-frags for Out-GEMM: chunk c=2D+cc, slot (H,j) -> d = 16c + rho(H,j)
        f16x8 ahf[4], alf[4];
#pragma unroll
        for (int D = 0; D < 2; ++D)
#pragma unroll
            for (int cc = 0; cc < 2; ++cc) {
                union { unsigned w[4]; f16x8 v; } uh, ul;
#pragma unroll
                for (int pp = 0; pp < 4; ++pp) {
                    const float v0 = oacc[tile][D][cc * 8 + 2 * pp]     * inv;
                    const float v1 = oacc[tile][D][cc * 8 + 2 * pp + 1] * inv;
                    const unsigned hu = pku(v0, v1);
                    const f16x2 hv = __builtin_bit_cast(f16x2, hu);
                    uh.w[pp] = hu;
                    ul.w[pp] = pku((v0 - (float)hv[0]) * 2048.0f, (v1 - (float)hv[1]) * 2048.0f);
                }
                ahf[2 * D + cc] = uh.v;
                alf[2 * D + cc] = ul.v;
            }

        const int hbase = h * HD;
        float* obase = Ypart + ((size_t)(s * NH + h) * ROWS + (size_t)b * Nseq
                                + qtile * BR + wave * 64 + tile * 32) * HD;

#pragma unroll
        for (int tn = 0; tn < 2; ++tn) {
            f32x16 chi = z16(), clo = z16();
            const float* wcol = W + (size_t)hbase * HD + 32 * tn + l31;
#pragma unroll
            for (int c = 0; c < 4; ++c) {
                // B-frag: slot (H,j) -> W[hbase + 16c + rho(H,j)][32tn + l31], hi/lo split
                union { unsigned w[4]; f16x8 v; } uwh, uwl;
#pragma unroll
                for (int pp = 0; pp < 4; ++pp) {
                    const int j0 = 2 * pp, j1 = 2 * pp + 1;
                    const int d0 = 16 * c + (j0 & 3) + 8 * (j0 >> 2) + 4 * H;
                    const int d1 = 16 * c + (j1 & 3) + 8 * (j1 >> 2) + 4 * H;
                    const float w0v = wcol[d0 * HD];
                    const float w1v = wcol[d1 * HD];
                    const unsigned hu = pku(w0v, w1v);
                    const f16x2 hv = __builtin_bit_cast(f16x2, hu);
                    uwh.w[pp] = hu;
                    uwl.w[pp] = pku((w0v - (float)hv[0]) * 2048.0f, (w1v - (float)hv[1]) * 2048.0f);
                }
                chi = mfma32(ahf[c], uwh.v, chi);
                clo = mfma32(ahf[c], uwl.v, clo);
                clo = mfma32(alf[c], uwh.v, clo);
            }
#pragma unroll
            for (int r = 0; r < 16; ++r) {
                const int q = (r & 3) + 8 * (r >> 2) + 4 * H;
                obase[(size_t)q * HD + 32 * tn + l31] = chi[r] + clo[r] * (1.0f / 2048.0f);
            }
        }
    }
}

// NSPLIT=1 combine: Out[i] = bias[i%64] + sum_h Y[h][i]
__global__ __launch_bounds__(256) void combine_kernel(
        const float* __restrict__ Ypart,
        const float* __restrict__ bias,
        float* __restrict__ Out) {
    const int i4 = (blockIdx.x * 256 + threadIdx.x) * 4;
    float4 acc = *(const float4*)(bias + (i4 & 63));
#pragma unroll
    for (int hh = 0; hh < NH; ++hh) {
        float4 p = *(const float4*)(Ypart + (size_t)hh * (ROWS * HD) + i4);
        acc.x += p.x; acc.y += p.y; acc.z += p.z; acc.w += p.w;
    }
    *(float4*)(Out + i4) = acc;
}

// NSPLIT>=2 combine: Out[q][j] = bias[j] + sum_h sum_s Y_s * l_s / (sum_s l_s)
template<int NSPLIT>
__global__ __launch_bounds__(256) void combineN_kernel(
        const float* __restrict__ Ypart,
        const float* __restrict__ lpart,
        const float* __restrict__ bias,
        float* __restrict__ Out) {
    const int i4 = (blockIdx.x * 256 + threadIdx.x) * 4;
    const int q  = i4 >> 6;
    const int j  = i4 & 63;
    float4 acc = *(const float4*)(bias + j);
#pragma unroll
    for (int hh = 0; hh < NH; ++hh) {
        float ls[NSPLIT];
        float lt = 0.f;
#pragma unroll
        for (int ss = 0; ss < NSPLIT; ++ss) {
            ls[ss] = lpart[(size_t)(ss * NH + hh) * ROWS + q];
            lt += ls[ss];
        }
        const float inv = 1.0f / lt;
#pragma unroll
        for (int ss = 0; ss < NSPLIT; ++ss) {
            const float w = ls[ss] * inv;
            const float4 y = *(const float4*)(Ypart + ((size_t)(ss * NH + hh) * ROWS + q) * HD + j);
            acc.x += y.x * w; acc.y += y.y * w; acc.z += y.z * w; acc.w += y.w * w;
        }
    }
    *(float4*)(Out + i4) = acc;
}

extern "C" void kernel_launch(void* const* d_in, const int* in_sizes, int n_in,
                              void* d_out, int out_size, void* d_ws, size_t ws_size,
                              hipStream_t stream) {
    (void)in_sizes; (void)n_in; (void)out_size;
    const float* Q    = (const float*)d_in[0];
    const float* K    = (const float*)d_in[1];
    const float* V    = (const float*)d_in[2];
    const float* W    = (const float*)d_in[3];
    const float* bias = (const float*)d_in[4];

    float* Y = (float*)d_ws;
    const size_t y2 = (size_t)2 * NH * ROWS * HD * sizeof(float);   // 32 MiB
    const size_t l2 = (size_t)2 * NH * ROWS * sizeof(float);        // 512 KiB

    if (ws_size >= y2 + l2) {
        float* lp = Y + (size_t)2 * NH * ROWS * HD;
        flash_attn_fused_kernel<2><<<dim3(2 * Nseq / BR * Bsz * NH), 256, 0, stream>>>(
            Q, K, V, W, Y, lp);
        combineN_kernel<2><<<dim3(ROWS * HD / 1024), 256, 0, stream>>>(Y, lp, bias, (float*)d_out);
    } else {
        flash_attn_fused_kernel<1><<<dim3(Nseq / BR * Bsz * NH), 256, 0, stream>>>(
            Q, K, V, W, Y, nullptr);
        combine_kernel<<<dim3(ROWS * HD / 1024), 256, 0, stream>>>(Y, bias, (float*)d_out);
    }
}

// Round 14
// 176.687 us; speedup vs baseline: 1.4121x; 1.4121x over previous
//
#include <hip/hip_runtime.h>
#include <cstdint>
#include <cstddef>

constexpr int Bsz   = 2;
constexpr int Nseq  = 4096;
constexpr int NH    = 8;
constexpr int HD    = 64;
constexpr int MODEL = NH * HD;   // 512
constexpr int BR    = 256;       // q-rows per block: 4 waves x 64 (2 subtiles of 32)
constexpr int BC    = 64;        // keys per tile (2 sub-tiles of 32)
constexpr int NT    = Nseq / BC; // 64 key tiles
constexpr int ROWS  = Bsz * Nseq;   // 8192

// 0.125 (1/sqrt(64)) * log2(e): exp(s) = exp2(s*log2e) with log2e folded into Q.
constexpr float QSCALE = 0.18033688011112042f;

typedef _Float16 f16;
typedef f16   f16x2 __attribute__((ext_vector_type(2)));
typedef f16   f16x8 __attribute__((ext_vector_type(8)));
typedef float f32x16 __attribute__((ext_vector_type(16)));

__device__ __forceinline__ unsigned pku(float a, float b) {
    auto r = __builtin_amdgcn_cvt_pkrtz(a, b);   // packed f32->f16 (RTZ), 1 instr
    return __builtin_bit_cast(unsigned, r);
}

__device__ __forceinline__ float fast_exp2(float x) {
#if __has_builtin(__builtin_amdgcn_exp2f)
    return __builtin_amdgcn_exp2f(x);
#else
    return exp2f(x);
#endif
}

__device__ __forceinline__ f32x16 z16() {
    f32x16 v;
#pragma unroll
    for (int i = 0; i < 16; ++i) v[i] = 0.f;
    return v;
}

__device__ __forceinline__ f32x16 mfma32(f16x8 a, f16x8 b, f32x16 c) {
    return __builtin_amdgcn_mfma_f32_32x32x16_f16(a, b, c, 0, 0, 0);
}

// Flash attention + fused per-head output projection.
// v13 = v11 (verified: 64 q-rows/wave, NSPLIT=2, 2 waves/SIMD, 128 VGPR no-spill,
// work cuts: no ones-MFMA l, log2e folded, f16-packed staging) with ONE change:
// the kt-body instruction ORDER. v12's lesson: the pipeline idea is right but any
// register growth spills (WRITE +45 MB). v13 reorders at ZERO register delta —
// pb split into two 16-reg halves (same 32 total as v11's pb[2][4]):
//    qk(0) -> exp(0) -> qk(1) -> pv(0) -> exp(1) -> stage/load -> pv(1)
// pv(0)'s 8 MFMAs (dep only on pb0) drain the matrix pipe while qk(1)'s
// accumulators complete, so exp(1) no longer eats the full MFMA latency
// (v11 diagnostic: MFMA 27% + VALU 33%, ~40% dependency stalls).
// Math identical to v7..v12 (all passed, absmax 4.9e-4): no-max-shift softmax,
// S^T = mfma(A=K,B=Q), operand-swapped PV O^T = mfma(A=V^T,B=P^T) (P in-lane;
// V staged with key-bits 2<->3 swapped -> contiguous b128 A-frags), l row-sum
// in VALU, fused split-f16 projection Y_s=(O_s/l_s)@W_h; combine sums
// sum_h sum_s Y_s*l_s/(sum_s l_s) + bias.
template<int NSPLIT>
__global__ __launch_bounds__(256, 2) void flash_attn_fused_kernel(
        const float* __restrict__ Q,
        const float* __restrict__ K,
        const float* __restrict__ V,
        const float* __restrict__ W,
        float* __restrict__ Ypart,
        float* __restrict__ lpart) {
    __shared__ __align__(16) f16 Ks[2][BC * 64];   // 2 x 8 KB  [key][d]
    __shared__ __align__(16) f16 Vt[2][HD * 64];   // 2 x 8 KB  [d][key]

    constexpr int NTL = NT / NSPLIT;   // key tiles per block

    const int wg = blockIdx.x;
    int qtile, bh, s;
    if constexpr (NSPLIT == 2) {
        // 512 blocks, 64 contiguous work-ids per XCD; both splits of one
        // (qtile,bh) on the same XCD -> K/V slices in its private L2 (v7: 25 MB).
        const int g = (wg & 7) * 64 + (wg >> 3);
        s = g & 1; qtile = (g >> 1) & 15; bh = g >> 5;
    } else {
        const int g = (wg & 7) * 32 + (wg >> 3);
        s = 0; qtile = g & 15; bh = g >> 4;
    }
    const int b   = bh >> 3;
    const int h   = bh & 7;
    const int kt0 = s * NTL;

    const int t    = threadIdx.x;
    const int lane = t & 63;
    const int wave = t >> 6;        // 0..3, 64 q-rows each
    const int l31  = lane & 31;
    const int H    = lane >> 5;     // half-wave

    // ---- Q fragments (B-operand: n=lane&31=q, chunk c: d = c*16 + H*8 + j); QSCALE folded ----
    f16x8 qf[2][4];
#pragma unroll
    for (int tile = 0; tile < 2; ++tile) {
        const int    qrow = qtile * BR + wave * 64 + tile * 32 + l31;
        const float* qp   = Q + ((size_t)(b * Nseq + qrow)) * MODEL + h * HD + H * 8;
#pragma unroll
        for (int c = 0; c < 4; ++c) {
            float4 a0 = *(const float4*)(qp + c * 16);
            float4 a1 = *(const float4*)(qp + c * 16 + 4);
            union { unsigned w[4]; f16x8 v; } u;
            u.w[0] = pku(a0.x * QSCALE, a0.y * QSCALE);
            u.w[1] = pku(a0.z * QSCALE, a0.w * QSCALE);
            u.w[2] = pku(a1.x * QSCALE, a1.y * QSCALE);
            u.w[3] = pku(a1.z * QSCALE, a1.w * QSCALE);
            qf[tile][c] = u.v;
        }
    }

    f32x16 oacc[2][2];   // [tile][D]: O^T[d = 32D + rho(H,r)][q = l31]
#pragma unroll
    for (int tile = 0; tile < 2; ++tile) {
        oacc[tile][0] = z16(); oacc[tile][1] = z16();
    }
    float lsum[2] = {0.f, 0.f};   // [tile]: partial denom over this lane's H-half keys

    // ---- staging assignments (256 threads) ----
    const int ka  = t & 7;          // K: chunk 0..7 (8 f16)
    const int kr  = t >> 3;         // K: rows kr and kr+32
    const int vkp = t & 31;         // V: key pair (keys 2vkp, 2vkp+1)
    // pi swaps key bits 2,3  ->  pair-index bits 1,2
    const int vps = (vkp & 0x19) | ((vkp & 2) << 1) | ((vkp & 4) >> 1);
    const int vd0 = (t >> 5) * 8;   // V: 8 d's

    // staging registers: already f16-packed (u32 pairs) -> 16 regs total
    unsigned kpk[8];   // [4*rr+i]: row kr+32rr, d-pair (2i,2i+1) of this thread's chunk
    unsigned vpk[8];   // [i]: d = vd0+i, keys (2vkp, 2vkp+1)

    auto loadtile = [&](int kt_) {   // kt_ is a GLOBAL tile index; packs to f16 at load
#pragma unroll
        for (int rr = 0; rr < 2; ++rr) {
            const float* kp = K + ((size_t)(b * Nseq + kt_ * BC + kr + 32 * rr)) * MODEL + h * HD + ka * 8;
            float4 a = *(const float4*)kp;
            float4 c = *(const float4*)(kp + 4);
            kpk[4 * rr + 0] = pku(a.x, a.y);
            kpk[4 * rr + 1] = pku(a.z, a.w);
            kpk[4 * rr + 2] = pku(c.x, c.y);
            kpk[4 * rr + 3] = pku(c.z, c.w);
        }
        const float* vp = V + ((size_t)(b * Nseq + kt_ * BC + 2 * vkp)) * MODEL + h * HD + vd0;
        float4 v0 = *(const float4*)vp;
        float4 v1 = *(const float4*)(vp + 4);
        float4 v2 = *(const float4*)(vp + MODEL);
        float4 v3 = *(const float4*)(vp + MODEL + 4);
        const float* e0 = &v0.x;   // key 2vkp,   d vd0..vd0+3
        const float* e1 = &v2.x;   // key 2vkp+1
#pragma unroll
        for (int i = 0; i < 4; ++i) vpk[i] = pku(e0[i], e1[i]);
        const float* f0 = &v1.x;   // key 2vkp,   d vd0+4..vd0+7
        const float* f1 = &v3.x;   // key 2vkp+1
#pragma unroll
        for (int i = 0; i < 4; ++i) vpk[4 + i] = pku(f0[i], f1[i]);
    };

    auto stage = [&](int pb_) {
        // K: full 8-f16 chunk per (row,chunk), b128 writes, swizzle chunk ^ (row&7)
#pragma unroll
        for (int rr = 0; rr < 2; ++rr) {
            const int row = kr + 32 * rr;
            union { unsigned w[4]; f16x8 v; } u;
            u.w[0] = kpk[4 * rr + 0]; u.w[1] = kpk[4 * rr + 1];
            u.w[2] = kpk[4 * rr + 2]; u.w[3] = kpk[4 * rr + 3];
            *(f16x8*)&Ks[pb_][row * 64 + ((ka ^ (row & 7)) << 3)] = u.v;
        }
        // V: transposed, pi-permuted pair position vps, 16B-chunk swizzle ^ (d&7)
#pragma unroll
        for (int i = 0; i < 8; ++i) {
            const int d = vd0 + i;
            *(unsigned*)&Vt[pb_][d * 64 + (((vps >> 2) ^ (d & 7)) << 3) + ((vps & 3) << 1)] = vpk[i];
        }
    };

    // ---- pipeline stage helpers (all statically indexed at call sites) ----
    auto qk_sub = [&](int T, f32x16 &sA, f32x16 &sB, int pbuf) {
        const int krow = T * 32 + l31;
        const int swz  = l31 & 7;
        __builtin_amdgcn_s_setprio(1);
#pragma unroll
        for (int c = 0; c < 4; ++c) {
            const f16x8 kf = *(const f16x8*)&Ks[pbuf][krow * 64 + (((2 * c + H) ^ swz) << 3)];
            sA = mfma32(kf, qf[0][c], sA);
            sB = mfma32(kf, qf[1][c], sB);
        }
        __builtin_amdgcn_s_setprio(0);
    };
    auto exp_sub = [&](const f32x16 &sA, const f32x16 &sB, f16x8 (&pbo)[2][2]) {
#pragma unroll
        for (int tile = 0; tile < 2; ++tile) {
            const f32x16 sv = tile ? sB : sA;
            union { unsigned w[4]; f16x8 v; } w0, w1;
            float a0 = 0.f, a1 = 0.f;
#pragma unroll
            for (int i = 0; i < 4; ++i) {
                float p0 = fast_exp2(sv[2 * i]);
                float p1 = fast_exp2(sv[2 * i + 1]);
                w0.w[i] = pku(p0, p1);
                a0 += p0 + p1;
            }
#pragma unroll
            for (int i = 0; i < 4; ++i) {
                float p0 = fast_exp2(sv[8 + 2 * i]);
                float p1 = fast_exp2(sv[8 + 2 * i + 1]);
                w1.w[i] = pku(p0, p1);
                a1 += p0 + p1;
            }
            lsum[tile] += a0 + a1;
            pbo[tile][0] = w0.v;
            pbo[tile][1] = w1.v;
        }
    };
    auto pv_sub = [&](int T, const f16x8 (&pbi)[2][2], int pbuf) {
        __builtin_amdgcn_s_setprio(1);
#pragma unroll
        for (int g = 0; g < 2; ++g) {
            const int gg = 2 * T + g;   // global frag group (16 keys each)
#pragma unroll
            for (int D = 0; D < 2; ++D) {
                const int d = D * 32 + l31;
                const f16x8 vf = *(const f16x8*)&Vt[pbuf][d * 64 + (((2 * gg + H) ^ (d & 7)) << 3)];
                oacc[0][D] = mfma32(vf, pbi[0][g], oacc[0][D]);
                oacc[1][D] = mfma32(vf, pbi[1][g], oacc[1][D]);
            }
        }
        __builtin_amdgcn_s_setprio(0);
    };

    // ---- prologue: buf0 <- tile kt0; regs <- tile kt0+1 ----
    loadtile(kt0);
    stage(0);
    loadtile(kt0 + 1);
    __syncthreads();

    int p = 0;
    for (int lt = 0; lt < NTL; ++lt) {
        f16x8 pb0[2][2], pb1[2][2];
        f32x16 sA = z16(), sB = z16();
        qk_sub(0, sA, sB, p);
        exp_sub(sA, sB, pb0);
        sA = z16(); sB = z16();
        qk_sub(1, sA, sB, p);
        pv_sub(0, pb0, p);          // MFMAs fill the qk(1)->exp(1) latency
        exp_sub(sA, sB, pb1);
        if (lt + 1 < NTL) stage(p ^ 1);
        if (lt + 2 < NTL) loadtile(kt0 + lt + 2);
        pv_sub(1, pb1, p);
        __syncthreads();   // buf[p^1] staged & visible; all reads of buf[p] done
        p ^= 1;
    }

    // ---- fused epilogue (per subtile): complete l, normalize, split-f16, W_h ----
#pragma unroll
    for (int tile = 0; tile < 2; ++tile) {
        // this lane holds the H-half partial; the complement lives at lane^32
        const float l_all = lsum[tile] + __shfl_xor(lsum[tile], 32, 64);
        const float inv   = 1.0f / l_all;

        if constexpr (NSPLIT >= 2) {   // store partial denominator
            if (H == 0)
                lpart[(size_t)(s * NH + h) * ROWS + b * Nseq
                      + qtile * BR + wave * 64 + tile * 32 + l31] = l_all;
        }

        // O^T regs -> A-frags for Out-GEMM: chunk c=2D+cc, slot (H,j) -> d = 16c + rho(H,j)
        f16x8 ahf[4], alf[4];
#pragma unroll
        for (int D = 0; D < 2; ++D)
#pragma unroll
            for (int cc = 0; cc < 2; ++cc) {
                union { unsigned w[4]; f16x8 v; } uh, ul;
#pragma unroll
                for (int pp = 0; pp < 4; ++pp) {
                    const float v0 = oacc[tile][D][cc * 8 + 2 * pp]     * inv;
                    const float v1 = oacc[tile][D][cc * 8 + 2 * pp + 1] * inv;
                    const unsigned hu = pku(v0, v1);
                    const f16x2 hv = __builtin_bit_cast(f16x2, hu);
                    uh.w[pp] = hu;
                    ul.w[pp] = pku((v0 - (float)hv[0]) * 2048.0f, (v1 - (float)hv[1]) * 2048.0f);
                }
                ahf[2 * D + cc] = uh.v;
                alf[2 * D + cc] = ul.v;
            }

        const int hbase = h * HD;
        float* obase = Ypart + ((size_t)(s * NH + h) * ROWS + (size_t)b * Nseq
                                + qtile * BR + wave * 64 + tile * 32) * HD;

#pragma unroll
        for (int tn = 0; tn < 2; ++tn) {
            f32x16 chi = z16(), clo = z16();
            const float* wcol = W + (size_t)hbase * HD + 32 * tn + l31;
#pragma unroll
            for (int c = 0; c < 4; ++c) {
                // B-frag: slot (H,j) -> W[hbase + 16c + rho(H,j)][32tn + l31], hi/lo split
                union { unsigned w[4]; f16x8 v; } uwh, uwl;
#pragma unroll
                for (int pp = 0; pp < 4; ++pp) {
                    const int j0 = 2 * pp, j1 = 2 * pp + 1;
                    const int d0 = 16 * c + (j0 & 3) + 8 * (j0 >> 2) + 4 * H;
                    const int d1 = 16 * c + (j1 & 3) + 8 * (j1 >> 2) + 4 * H;
                    const float w0v = wcol[d0 * HD];
                    const float w1v = wcol[d1 * HD];
                    const unsigned hu = pku(w0v, w1v);
                    const f16x2 hv = __builtin_bit_cast(f16x2, hu);
                    uwh.w[pp] = hu;
                    uwl.w[pp] = pku((w0v - (float)hv[0]) * 2048.0f, (w1v - (float)hv[1]) * 2048.0f);
                }
                chi = mfma32(ahf[c], uwh.v, chi);
                clo = mfma32(ahf[c], uwl.v, clo);
                clo = mfma32(alf[c], uwh.v, clo);
            }
#pragma unroll
            for (int r = 0; r < 16; ++r) {
                const int q = (r & 3) + 8 * (r >> 2) + 4 * H;
                obase[(size_t)q * HD + 32 * tn + l31] = chi[r] + clo[r] * (1.0f / 2048.0f);
            }
        }
    }
}

// NSPLIT=1 combine: Out[i] = bias[i%64] + sum_h Y[h][i]
__global__ __launch_bounds__(256) void combine_kernel(
        const float* __restrict__ Ypart,
        const float* __restrict__ bias,
        float* __restrict__ Out) {
    const int i4 = (blockIdx.x * 256 + threadIdx.x) * 4;
    float4 acc = *(const float4*)(bias + (i4 & 63));
#pragma unroll
    for (int hh = 0; hh < NH; ++hh) {
        float4 p = *(const float4*)(Ypart + (size_t)hh * (ROWS * HD) + i4);
        acc.x += p.x; acc.y += p.y; acc.z += p.z; acc.w += p.w;
    }
    *(float4*)(Out + i4) = acc;
}

// NSPLIT>=2 combine: Out[q][j] = bias[j] + sum_h sum_s Y_s * l_s / (sum_s l_s)
template<int NSPLIT>
__global__ __launch_bounds__(256) void combineN_kernel(
        const float* __restrict__ Ypart,
        const float* __restrict__ lpart,
        const float* __restrict__ bias,
        float* __restrict__ Out) {
    const int i4 = (blockIdx.x * 256 + threadIdx.x) * 4;
    const int q  = i4 >> 6;
    const int j  = i4 & 63;
    float4 acc = *(const float4*)(bias + j);
#pragma unroll
    for (int hh = 0; hh < NH; ++hh) {
        float ls[NSPLIT];
        float lt = 0.f;
#pragma unroll
        for (int ss = 0; ss < NSPLIT; ++ss) {
            ls[ss] = lpart[(size_t)(ss * NH + hh) * ROWS + q];
            lt += ls[ss];
        }
        const float inv = 1.0f / lt;
#pragma unroll
        for (int ss = 0; ss < NSPLIT; ++ss) {
            const float w = ls[ss] * inv;
            const float4 y = *(const float4*)(Ypart + ((size_t)(ss * NH + hh) * ROWS + q) * HD + j);
            acc.x += y.x * w; acc.y += y.y * w; acc.z += y.z * w; acc.w += y.w * w;
        }
    }
    *(float4*)(Out + i4) = acc;
}

extern "C" void kernel_launch(void* const* d_in, const int* in_sizes, int n_in,
                              void* d_out, int out_size, void* d_ws, size_t ws_size,
                              hipStream_t stream) {
    (void)in_sizes; (void)n_in; (void)out_size;
    const float* Q    = (const float*)d_in[0];
    const float* K    = (const float*)d_in[1];
    const float* V    = (const float*)d_in[2];
    const float* W    = (const float*)d_in[3];
    const float* bias = (const float*)d_in[4];

    float* Y = (float*)d_ws;
    const size_t y2 = (size_t)2 * NH * ROWS * HD * sizeof(float);   // 32 MiB
    const size_t l2 = (size_t)2 * NH * ROWS * sizeof(float);        // 512 KiB

    if (ws_size >= y2 + l2) {
        float* lp = Y + (size_t)2 * NH * ROWS * HD;
        flash_attn_fused_kernel<2><<<dim3(2 * Nseq / BR * Bsz * NH), 256, 0, stream>>>(
            Q, K, V, W, Y, lp);
        combineN_kernel<2><<<dim3(ROWS * HD / 1024), 256, 0, stream>>>(Y, lp, bias, (float*)d_out);
    } else {
        flash_attn_fused_kernel<1><<<dim3(Nseq / BR * Bsz * NH), 256, 0, stream>>>(
            Q, K, V, W, Y, nullptr);
        combine_kernel<<<dim3(ROWS * HD / 1024), 256, 0, stream>>>(Y, bias, (float*)d_out);
    }
}